// Round 4
// baseline (529.001 us; speedup 1.0000x reference)
//
#include <hip/hip_runtime.h>

#define N_ROWS 32768
#define DIM 256
#define KCODES 1024

#define Q_N (N_ROWS * DIM)          // 8388608
#define IDX_OFF Q_N                 // 8388608
#define ZERO_OFF (Q_N + N_ROWS)     // 8421376
#define LOSS_OFF (ZERO_OFF + 1)
#define PERP_OFF (ZERO_OFF + 2)

// score-scale margin below which np's fp32 rounding could change the argmin;
// fast path (bf16 3-split MFMA) error ~5e-6 worst-case, np quantization ~6e-5.
#define THETA 2.0e-4f

typedef __attribute__((ext_vector_type(8))) short bf16x8;
typedef __attribute__((ext_vector_type(4))) float f32x4;
typedef unsigned short u16;

// ws layout (bytes):
//   [0, 4096)          sen float[K]
//   [4096, 8192)       hist uint[K]
//   [8192, 8200)       double loss_acc
//   [8200, 8204)       uint ambig_count
//   [8448, 139520)     szn float[32768]  (numpy-pairwise ||z||^2)
//   [139520, 270592)   uint worklist[32768]
//   [270592, 794880)   ehi u16[262144]   (bf16 of -e)
//   [794880, 1319168)  elo u16[262144]   (bf16 of (-e) - ehi)
// zhi/zlo (16.78 MB each) live in d_out's q region [0, 33.55 MB) until vq_gather
// overwrites it at the end of the sequence.

__device__ inline u16 bf16rne(float f) {
    unsigned u = __float_as_uint(f);
    return (u16)((u + 0x7FFFu + ((u >> 16) & 1u)) >> 16);
}
__device__ inline float bf16f(u16 h) { return __uint_as_float((unsigned)h << 16); }

__global__ __launch_bounds__(1024) void vq_init(unsigned* __restrict__ hist,
                                                double* __restrict__ loss_acc,
                                                unsigned* __restrict__ count) {
    int t = threadIdx.x;
    if (t < KCODES) hist[t] = 0u;
    if (t == 0) { *loss_acc = 0.0; *count = 0u; }
}

// accurate ||e_k||^2: fp64 accumulate -> fp32
__global__ __launch_bounds__(256) void vq_sen(const float* __restrict__ cb,
                                              float* __restrict__ sen) {
    int w = blockIdx.x * 4 + (threadIdx.x >> 6);
    int lane = threadIdx.x & 63;
    float4 v = *(const float4*)(cb + (size_t)w * DIM + lane * 4);
    double s = (double)v.x * v.x + (double)v.y * v.y + (double)v.z * v.z + (double)v.w * v.w;
    #pragma unroll
    for (int off = 32; off; off >>= 1) s += __shfl_down(s, off, 64);
    if (lane == 0) sen[w] = (float)s;
}

// ||z_row||^2 emulating numpy fp32 pairwise_sum for n=256 (see round-3 notes)
__global__ __launch_bounds__(256) void vq_szn(const float* __restrict__ z,
                                              float* __restrict__ szn) {
    int lane = threadIdx.x & 63;
    int waveInBlk = threadIdx.x >> 6;
    int rowInWave = lane >> 4;
    int sub = lane & 15;
    int h = sub >> 3;
    int j = sub & 7;
    int row = (blockIdx.x * 4 + waveInBlk) * 4 + rowInWave;
    const float* a = z + (size_t)row * DIM + h * 128 + j;
    float v0 = a[0];
    float c = __fmul_rn(v0, v0);
    #pragma unroll
    for (int i = 1; i < 16; ++i) {
        float v = a[8 * i];
        c = __fadd_rn(c, __fmul_rn(v, v));
    }
    float p;
    p = __shfl_xor(c, 1, 64); c = __fadd_rn(c, p);
    p = __shfl_xor(c, 2, 64); c = __fadd_rn(c, p);
    p = __shfl_xor(c, 4, 64); c = __fadd_rn(c, p);
    p = __shfl_xor(c, 8, 64); c = __fadd_rn(c, p);
    if (sub == 0) szn[row] = c;
}

// z -> bf16 hi/lo splits (z = hi + lo + O(2^-18 |z|))
__global__ __launch_bounds__(256) void vq_split_z(const float* __restrict__ z,
                                                  u16* __restrict__ zhi,
                                                  u16* __restrict__ zlo) {
    size_t gid = (size_t)blockIdx.x * 256 + threadIdx.x;
    float4 v = *(const float4*)(z + gid * 4);
    ushort4 h, l;
    h.x = bf16rne(v.x); l.x = bf16rne(v.x - bf16f(h.x));
    h.y = bf16rne(v.y); l.y = bf16rne(v.y - bf16f(h.y));
    h.z = bf16rne(v.z); l.z = bf16rne(v.z - bf16f(h.z));
    h.w = bf16rne(v.w); l.w = bf16rne(v.w - bf16f(h.w));
    *(ushort4*)(zhi + gid * 4) = h;
    *(ushort4*)(zlo + gid * 4) = l;
}

// codebook -> NEGATED bf16 hi/lo splits (so MFMA accumulates -dot)
__global__ __launch_bounds__(256) void vq_split_e(const float* __restrict__ cb,
                                                  u16* __restrict__ ehi,
                                                  u16* __restrict__ elo) {
    size_t gid = (size_t)blockIdx.x * 256 + threadIdx.x;
    float4 v = *(const float4*)(cb + gid * 4);
    v.x = -v.x; v.y = -v.y; v.z = -v.z; v.w = -v.w;
    ushort4 h, l;
    h.x = bf16rne(v.x); l.x = bf16rne(v.x - bf16f(h.x));
    h.y = bf16rne(v.y); l.y = bf16rne(v.y - bf16f(h.y));
    h.z = bf16rne(v.z); l.z = bf16rne(v.z - bf16f(h.z));
    h.w = bf16rne(v.w); l.w = bf16rne(v.w - bf16f(h.w));
    *(ushort4*)(ehi + gid * 4) = h;
    *(ushort4*)(elo + gid * 4) = l;
}

// MFMA distance-argmin: 256 blocks x 8 waves; wave owns 16 rows (fragments in
// 64 VGPRs), loops all 1024 codes in 16-code tiles. acc = 0.5*sen - dot = score/2.
__global__ __launch_bounds__(512) void vq_mfma(const u16* __restrict__ zhi,
                                               const u16* __restrict__ zlo,
                                               const u16* __restrict__ ehi,
                                               const u16* __restrict__ elo,
                                               const float* __restrict__ sen,
                                               float* __restrict__ idx_out,
                                               unsigned* __restrict__ count,
                                               unsigned* __restrict__ worklist) {
    const int tid = threadIdx.x;
    const int wid = tid >> 6;
    const int lane = tid & 63;
    const int col16 = lane & 15;   // A: z-row selector / B: e-row (code) / C: col
    const int koct = lane >> 4;    // k-octet selector
    const int rowbase = blockIdx.x * 128 + wid * 16;
    const int zrow = rowbase + col16;

    // preload this wave's z fragments: 8 d-chunks x {hi,lo}
    bf16x8 zh[8], zl[8];
    {
        const u16* ph = zhi + (size_t)zrow * DIM + koct * 8;
        const u16* pl = zlo + (size_t)zrow * DIM + koct * 8;
        #pragma unroll
        for (int dc = 0; dc < 8; ++dc) {
            zh[dc] = *(const bf16x8*)(ph + dc * 32);
            zl[dc] = *(const bf16x8*)(pl + dc * 32);
        }
    }

    float best[4]   = {3.4e38f, 3.4e38f, 3.4e38f, 3.4e38f};
    float second[4] = {3.4e38f, 3.4e38f, 3.4e38f, 3.4e38f};
    int   besti[4]  = {0, 0, 0, 0};

    const u16* ehp = ehi + (size_t)col16 * DIM + koct * 8;
    const u16* elp = elo + (size_t)col16 * DIM + koct * 8;

    for (int ct = 0; ct < 64; ++ct) {
        const int c = ct * 16 + col16;
        const float sh = 0.5f * sen[c];
        f32x4 acc = {sh, sh, sh, sh};
        const u16* eh = ehp + (size_t)ct * 16 * DIM;
        const u16* el = elp + (size_t)ct * 16 * DIM;
        #pragma unroll
        for (int dc = 0; dc < 8; ++dc) {
            bf16x8 bh = *(const bf16x8*)(eh + dc * 32);
            bf16x8 bl = *(const bf16x8*)(el + dc * 32);
            acc = __builtin_amdgcn_mfma_f32_16x16x32_bf16(zh[dc], bh, acc, 0, 0, 0);
            acc = __builtin_amdgcn_mfma_f32_16x16x32_bf16(zl[dc], bh, acc, 0, 0, 0);
            acc = __builtin_amdgcn_mfma_f32_16x16x32_bf16(zh[dc], bl, acc, 0, 0, 0);
        }
        #pragma unroll
        for (int r = 0; r < 4; ++r) {
            float s = acc[r];
            if (s < best[r]) { second[r] = best[r]; best[r] = s; besti[r] = c; }
            else if (s < second[r]) { second[r] = s; }
        }
    }

    #pragma unroll
    for (int r = 0; r < 4; ++r) {
        float v1 = best[r], v2 = second[r];
        int i1 = besti[r];
        #pragma unroll
        for (int m = 1; m < 16; m <<= 1) {
            float ov1 = __shfl_xor(v1, m, 64);
            int   oi1 = __shfl_xor(i1, m, 64);
            float ov2 = __shfl_xor(v2, m, 64);
            if (ov1 < v1 || (ov1 == v1 && oi1 < i1)) {
                v2 = fminf(v1, ov2); v1 = ov1; i1 = oi1;
            } else {
                v2 = fminf(v2, ov1);
            }
        }
        if (col16 == 0) {
            int row = rowbase + koct * 4 + r;
            idx_out[row] = (float)i1;
            if (v2 - v1 < 0.5f * THETA) {   // acc is score/2
                unsigned slot = atomicAdd(count, 1u);
                worklist[slot] = (unsigned)row;
            }
        }
    }
}

// np-fp32 emulation for ambiguous rows (bit-exact vs reference argmin)
__global__ __launch_bounds__(256) void vq_fixup(const float* __restrict__ z,
                                                const float* __restrict__ cb,
                                                const float* __restrict__ sen,
                                                const float* __restrict__ szn,
                                                const unsigned* __restrict__ count,
                                                const unsigned* __restrict__ worklist,
                                                float* __restrict__ idx_out) {
    __shared__ float zrow[DIM];
    __shared__ float rv[256];
    __shared__ int ri[256];
    int t = threadIdx.x;
    int n = (int)*count;
    for (int w = blockIdx.x; w < n; w += gridDim.x) {
        int row = (int)worklist[w];
        float sz = szn[row];
        zrow[t] = z[(size_t)row * DIM + t];
        __syncthreads();
        float bv = 3.4e38f;
        int bi = 0x7fffffff;
        #pragma unroll
        for (int cc = 0; cc < 4; ++cc) {
            int cI = t + 256 * cc;
            const float* e = cb + (size_t)cI * DIM;
            double dot = 0.0;
            for (int d = 0; d < DIM; d += 4) {
                float4 ev = *(const float4*)(e + d);
                dot += (double)ev.x * zrow[d + 0] + (double)ev.y * zrow[d + 1]
                     + (double)ev.z * zrow[d + 2] + (double)ev.w * zrow[d + 3];
            }
            float dotx = (float)dot;
            float A = __fadd_rn(sz, sen[cI]);
            float dref = __fmaf_rn(-2.0f, dotx, A);
            if (dref < bv) { bv = dref; bi = cI; }
        }
        rv[t] = bv; ri[t] = bi;
        __syncthreads();
        for (int s = 128; s; s >>= 1) {
            if (t < s) {
                if (rv[t + s] < rv[t] || (rv[t + s] == rv[t] && ri[t + s] < ri[t])) {
                    rv[t] = rv[t + s]; ri[t] = ri[t + s];
                }
            }
            __syncthreads();
        }
        if (t == 0) idx_out[row] = (float)ri[0];
        __syncthreads();
    }
}

// quantized_ste = z + (q - z); commitment loss; histogram from final idx
__global__ __launch_bounds__(256) void vq_gather(const float* __restrict__ z,
                                                 const float* __restrict__ cb,
                                                 const float* __restrict__ idxf,
                                                 float* __restrict__ qout,
                                                 double* __restrict__ loss_acc,
                                                 unsigned* __restrict__ hist) {
    int gid = blockIdx.x * 256 + threadIdx.x;
    int row = gid >> 6, c4 = gid & 63;
    int idx = (int)idxf[row];
    if (c4 == 0) atomicAdd(&hist[idx], 1u);
    float4 zv = *(const float4*)(z + (size_t)row * DIM + c4 * 4);
    float4 qv = *(const float4*)(cb + (size_t)idx * DIM + c4 * 4);
    float dx = qv.x - zv.x, dy = qv.y - zv.y, dz = qv.z - zv.z, dw = qv.w - zv.w;
    float4 o;
    o.x = zv.x + dx; o.y = zv.y + dy; o.z = zv.z + dz; o.w = zv.w + dw;
    *(float4*)(qout + (size_t)row * DIM + c4 * 4) = o;
    float ls = dx * dx + dy * dy + dz * dz + dw * dw;
    #pragma unroll
    for (int off = 32; off; off >>= 1) ls += __shfl_down(ls, off, 64);
    __shared__ float wsum[4];
    int lane = threadIdx.x & 63, wv = threadIdx.x >> 6;
    if (lane == 0) wsum[wv] = ls;
    __syncthreads();
    if (threadIdx.x == 0)
        atomicAdd(loss_acc, (double)(wsum[0] + wsum[1] + wsum[2] + wsum[3]));
}

__global__ __launch_bounds__(1024) void vq_finalize(const unsigned* __restrict__ hist,
                                                    const double* __restrict__ loss_acc,
                                                    float* __restrict__ out) {
    __shared__ float red[1024];
    int t = threadIdx.x;
    float p = (float)hist[t] * (1.0f / (float)N_ROWS);
    red[t] = p * logf(p + 1e-10f);
    __syncthreads();
    for (int s = 512; s; s >>= 1) {
        if (t < s) red[t] += red[t + s];
        __syncthreads();
    }
    if (t == 0) {
        out[ZERO_OFF] = 0.0f;
        out[LOSS_OFF] = (float)(0.25 * (*loss_acc) / (double)Q_N);
        out[PERP_OFF] = expf(-red[0]);
    }
}

extern "C" void kernel_launch(void* const* d_in, const int* in_sizes, int n_in,
                              void* d_out, int out_size, void* d_ws, size_t ws_size,
                              hipStream_t stream) {
    const float* z = (const float*)d_in[0];
    const float* cb = (const float*)d_in[1];
    float* out = (float*)d_out;

    float* sen = (float*)d_ws;
    unsigned* hist = (unsigned*)((char*)d_ws + 4096);
    double* loss_acc = (double*)((char*)d_ws + 8192);
    unsigned* count = (unsigned*)((char*)d_ws + 8200);
    float* szn = (float*)((char*)d_ws + 8448);
    unsigned* worklist = (unsigned*)((char*)d_ws + 139520);
    u16* ehi = (u16*)((char*)d_ws + 270592);
    u16* elo = (u16*)((char*)d_ws + 794880);

    // z splits live in d_out's q region until vq_gather overwrites it
    u16* zhi = (u16*)d_out;
    u16* zlo = (u16*)d_out + Q_N;

    vq_init<<<1, 1024, 0, stream>>>(hist, loss_acc, count);
    vq_sen<<<KCODES / 4, 256, 0, stream>>>(cb, sen);
    vq_szn<<<N_ROWS / 16, 256, 0, stream>>>(z, szn);
    vq_split_z<<<Q_N / 1024, 256, 0, stream>>>(z, zhi, zlo);
    vq_split_e<<<(KCODES * DIM) / 1024, 256, 0, stream>>>(cb, ehi, elo);
    vq_mfma<<<N_ROWS / 128, 512, 0, stream>>>(zhi, zlo, ehi, elo, sen,
                                              out + IDX_OFF, count, worklist);
    vq_fixup<<<256, 256, 0, stream>>>(z, cb, sen, szn, count, worklist, out + IDX_OFF);
    vq_gather<<<(N_ROWS * (DIM / 4)) / 256, 256, 0, stream>>>(z, cb, out + IDX_OFF, out, loss_acc, hist);
    vq_finalize<<<1, 1024, 0, stream>>>(hist, loss_acc, out);
}

// Round 5
// 524.380 us; speedup vs baseline: 1.0088x; 1.0088x over previous
//
#include <hip/hip_runtime.h>

#define N_ROWS 32768
#define DIM 256
#define KCODES 1024

#define Q_N (N_ROWS * DIM)          // 8388608
#define IDX_OFF Q_N                 // 8388608
#define ZERO_OFF (Q_N + N_ROWS)     // 8421376
#define LOSS_OFF (ZERO_OFF + 1)
#define PERP_OFF (ZERO_OFF + 2)

// score-scale margin below which np's fp32 rounding could change the argmin;
// fast path (bf16 3-split MFMA) error ~3e-5 worst-case, np quantization ~6e-5.
#define THETA 2.0e-4f

typedef __attribute__((ext_vector_type(8))) short bf16x8;
typedef __attribute__((ext_vector_type(4))) float f32x4;
typedef unsigned short u16;

// ws layout (bytes):
//   [0, 4096)          sen float[K]
//   [4096, 8192)       hist uint[K]
//   [8192, 8200)       double loss_acc
//   [8200, 8204)       uint ambig_count
//   [8448, 139520)     szn float[32768]  (numpy-pairwise ||z||^2)
//   [139520, 270592)   uint worklist[32768]
//   [270592, 794880)   ehi u16[262144]   (bf16 of -e)
//   [794880, 1319168)  elo u16[262144]   (bf16 of (-e) - ehi)
// zhi/zlo (16.78 MB each) live in d_out's q region until vq_gather overwrites it.

__device__ inline u16 bf16rne(float f) {
    unsigned u = __float_as_uint(f);
    return (u16)((u + 0x7FFFu + ((u >> 16) & 1u)) >> 16);
}
__device__ inline float bf16f(u16 h) { return __uint_as_float((unsigned)h << 16); }

__global__ __launch_bounds__(1024) void vq_init(unsigned* __restrict__ hist,
                                                double* __restrict__ loss_acc,
                                                unsigned* __restrict__ count) {
    int t = threadIdx.x;
    if (t < KCODES) hist[t] = 0u;
    if (t == 0) { *loss_acc = 0.0; *count = 0u; }
}

// accurate ||e_k||^2: fp64 accumulate -> fp32
__global__ __launch_bounds__(256) void vq_sen(const float* __restrict__ cb,
                                              float* __restrict__ sen) {
    int w = blockIdx.x * 4 + (threadIdx.x >> 6);
    int lane = threadIdx.x & 63;
    float4 v = *(const float4*)(cb + (size_t)w * DIM + lane * 4);
    double s = (double)v.x * v.x + (double)v.y * v.y + (double)v.z * v.z + (double)v.w * v.w;
    #pragma unroll
    for (int off = 32; off; off >>= 1) s += __shfl_down(s, off, 64);
    if (lane == 0) sen[w] = (float)s;
}

// fused: z -> bf16 hi/lo splits + numpy-pairwise-exact ||z||^2.
// block = 256 threads = 4 rows (1024 floats). Phase A: coalesced float4 read,
// emit splits, stash z in LDS. Phase B: 16 lanes/row replicate np's fp32
// pairwise_sum order exactly (8 accumulators x 16 sequential steps per
// 128-block, fixed combine tree) via __fmul_rn/__fadd_rn.
__global__ __launch_bounds__(256) void vq_prep_z(const float* __restrict__ z,
                                                 u16* __restrict__ zhi,
                                                 u16* __restrict__ zlo,
                                                 float* __restrict__ szn) {
    __shared__ float zs[4 * 264];   // stride 264 floats: de-conflicts stride-8 reads
    size_t base = (size_t)blockIdx.x * 1024;
    int t = threadIdx.x;
    float4 v = *(const float4*)(z + base + t * 4);
    ushort4 h, l;
    h.x = bf16rne(v.x); l.x = bf16rne(v.x - bf16f(h.x));
    h.y = bf16rne(v.y); l.y = bf16rne(v.y - bf16f(h.y));
    h.z = bf16rne(v.z); l.z = bf16rne(v.z - bf16f(h.z));
    h.w = bf16rne(v.w); l.w = bf16rne(v.w - bf16f(h.w));
    *(ushort4*)(zhi + base + t * 4) = h;
    *(ushort4*)(zlo + base + t * 4) = l;
    int rowA = t >> 6, dA = (t & 63) * 4;
    *(float4*)&zs[rowA * 264 + dA] = v;
    __syncthreads();
    if (t < 64) {
        int rowL = t >> 4;          // 4 rows
        int sub = t & 15;           // 16 lanes per row
        int hb = sub >> 3;          // which 128-block
        int j = sub & 7;            // np accumulator index
        const float* a = zs + rowL * 264 + hb * 128 + j;
        float v0 = a[0];
        float c = __fmul_rn(v0, v0);
        #pragma unroll
        for (int i = 1; i < 16; ++i) {
            float w = a[8 * i];
            c = __fadd_rn(c, __fmul_rn(w, w));
        }
        float p;
        p = __shfl_xor(c, 1, 64); c = __fadd_rn(c, p);
        p = __shfl_xor(c, 2, 64); c = __fadd_rn(c, p);
        p = __shfl_xor(c, 4, 64); c = __fadd_rn(c, p);
        p = __shfl_xor(c, 8, 64); c = __fadd_rn(c, p);
        if (sub == 0) szn[blockIdx.x * 4 + rowL] = c;
    }
}

// codebook -> NEGATED bf16 hi/lo splits (so MFMA accumulates -dot)
__global__ __launch_bounds__(256) void vq_split_e(const float* __restrict__ cb,
                                                  u16* __restrict__ ehi,
                                                  u16* __restrict__ elo) {
    size_t gid = (size_t)blockIdx.x * 256 + threadIdx.x;
    float4 v = *(const float4*)(cb + gid * 4);
    v.x = -v.x; v.y = -v.y; v.z = -v.z; v.w = -v.w;
    ushort4 h, l;
    h.x = bf16rne(v.x); l.x = bf16rne(v.x - bf16f(h.x));
    h.y = bf16rne(v.y); l.y = bf16rne(v.y - bf16f(h.y));
    h.z = bf16rne(v.z); l.z = bf16rne(v.z - bf16f(h.z));
    h.w = bf16rne(v.w); l.w = bf16rne(v.w - bf16f(h.w));
    *(ushort4*)(ehi + gid * 4) = h;
    *(ushort4*)(elo + gid * 4) = l;
}

// MFMA distance-argmin: 256 blocks x 8 waves; wave owns 16 rows (fragments kept
// in 64 VGPRs — launch_bounds(512,2) caps at 256 VGPR so NO spill), loops all
// 1024 codes in 16-code tiles. Three independent MFMA chains (hi*hi, lo*hi,
// hi*lo) break the 24-deep acc dependency; score/2 = 0.5*sen + sum of chains.
__global__ __launch_bounds__(512, 2) void vq_mfma(const u16* __restrict__ zhi,
                                                  const u16* __restrict__ zlo,
                                                  const u16* __restrict__ ehi,
                                                  const u16* __restrict__ elo,
                                                  const float* __restrict__ sen,
                                                  float* __restrict__ idx_out,
                                                  unsigned* __restrict__ count,
                                                  unsigned* __restrict__ worklist) {
    const int tid = threadIdx.x;
    const int wid = tid >> 6;
    const int lane = tid & 63;
    const int col16 = lane & 15;
    const int koct = lane >> 4;
    const int rowbase = blockIdx.x * 128 + wid * 16;
    const int zrow = rowbase + col16;

    bf16x8 zh[8], zl[8];
    {
        const u16* ph = zhi + (size_t)zrow * DIM + koct * 8;
        const u16* pl = zlo + (size_t)zrow * DIM + koct * 8;
        #pragma unroll
        for (int dc = 0; dc < 8; ++dc) {
            zh[dc] = *(const bf16x8*)(ph + dc * 32);
            zl[dc] = *(const bf16x8*)(pl + dc * 32);
        }
    }

    float best[4]   = {3.4e38f, 3.4e38f, 3.4e38f, 3.4e38f};
    float second[4] = {3.4e38f, 3.4e38f, 3.4e38f, 3.4e38f};
    int   besti[4]  = {0, 0, 0, 0};

    const u16* ehp = ehi + (size_t)col16 * DIM + koct * 8;
    const u16* elp = elo + (size_t)col16 * DIM + koct * 8;

    for (int ct = 0; ct < 64; ++ct) {
        const int c = ct * 16 + col16;
        const float sh = 0.5f * sen[c];     // issued early, consumed in epilogue
        const u16* eh = ehp + (size_t)ct * 16 * DIM;
        const u16* el = elp + (size_t)ct * 16 * DIM;
        f32x4 aHH = {0.f, 0.f, 0.f, 0.f};
        f32x4 aLH = {0.f, 0.f, 0.f, 0.f};
        f32x4 aHL = {0.f, 0.f, 0.f, 0.f};
        #pragma unroll
        for (int dc = 0; dc < 8; ++dc) {
            bf16x8 bh = *(const bf16x8*)(eh + dc * 32);
            bf16x8 bl = *(const bf16x8*)(el + dc * 32);
            aHH = __builtin_amdgcn_mfma_f32_16x16x32_bf16(zh[dc], bh, aHH, 0, 0, 0);
            aLH = __builtin_amdgcn_mfma_f32_16x16x32_bf16(zl[dc], bh, aLH, 0, 0, 0);
            aHL = __builtin_amdgcn_mfma_f32_16x16x32_bf16(zh[dc], bl, aHL, 0, 0, 0);
        }
        #pragma unroll
        for (int r = 0; r < 4; ++r) {
            float s = sh + (aHH[r] + (aLH[r] + aHL[r]));
            if (s < best[r]) { second[r] = best[r]; best[r] = s; besti[r] = c; }
            else if (s < second[r]) { second[r] = s; }
        }
    }

    #pragma unroll
    for (int r = 0; r < 4; ++r) {
        float v1 = best[r], v2 = second[r];
        int i1 = besti[r];
        #pragma unroll
        for (int m = 1; m < 16; m <<= 1) {
            float ov1 = __shfl_xor(v1, m, 64);
            int   oi1 = __shfl_xor(i1, m, 64);
            float ov2 = __shfl_xor(v2, m, 64);
            if (ov1 < v1 || (ov1 == v1 && oi1 < i1)) {
                v2 = fminf(v1, ov2); v1 = ov1; i1 = oi1;
            } else {
                v2 = fminf(v2, ov1);
            }
        }
        if (col16 == 0) {
            int row = rowbase + koct * 4 + r;
            idx_out[row] = (float)i1;
            if (v2 - v1 < 0.5f * THETA) {   // acc is score/2
                unsigned slot = atomicAdd(count, 1u);
                worklist[slot] = (unsigned)row;
            }
        }
    }
}

// np-fp32 emulation for ambiguous rows (bit-exact vs reference argmin)
__global__ __launch_bounds__(256) void vq_fixup(const float* __restrict__ z,
                                                const float* __restrict__ cb,
                                                const float* __restrict__ sen,
                                                const float* __restrict__ szn,
                                                const unsigned* __restrict__ count,
                                                const unsigned* __restrict__ worklist,
                                                float* __restrict__ idx_out) {
    __shared__ float zrow[DIM];
    __shared__ float rv[256];
    __shared__ int ri[256];
    int t = threadIdx.x;
    int n = (int)*count;
    for (int w = blockIdx.x; w < n; w += gridDim.x) {
        int row = (int)worklist[w];
        float sz = szn[row];
        zrow[t] = z[(size_t)row * DIM + t];
        __syncthreads();
        float bv = 3.4e38f;
        int bi = 0x7fffffff;
        #pragma unroll
        for (int cc = 0; cc < 4; ++cc) {
            int cI = t + 256 * cc;
            const float* e = cb + (size_t)cI * DIM;
            double dot = 0.0;
            for (int d = 0; d < DIM; d += 4) {
                float4 ev = *(const float4*)(e + d);
                dot += (double)ev.x * zrow[d + 0] + (double)ev.y * zrow[d + 1]
                     + (double)ev.z * zrow[d + 2] + (double)ev.w * zrow[d + 3];
            }
            float dotx = (float)dot;
            float A = __fadd_rn(sz, sen[cI]);
            float dref = __fmaf_rn(-2.0f, dotx, A);
            if (dref < bv) { bv = dref; bi = cI; }
        }
        rv[t] = bv; ri[t] = bi;
        __syncthreads();
        for (int s = 128; s; s >>= 1) {
            if (t < s) {
                if (rv[t + s] < rv[t] || (rv[t + s] == rv[t] && ri[t + s] < ri[t])) {
                    rv[t] = rv[t + s]; ri[t] = ri[t + s];
                }
            }
            __syncthreads();
        }
        if (t == 0) idx_out[row] = (float)ri[0];
        __syncthreads();
    }
}

// quantized_ste = z + (q - z); commitment loss; histogram from final idx
__global__ __launch_bounds__(256) void vq_gather(const float* __restrict__ z,
                                                 const float* __restrict__ cb,
                                                 const float* __restrict__ idxf,
                                                 float* __restrict__ qout,
                                                 double* __restrict__ loss_acc,
                                                 unsigned* __restrict__ hist) {
    int gid = blockIdx.x * 256 + threadIdx.x;
    int row = gid >> 6, c4 = gid & 63;
    int idx = (int)idxf[row];
    if (c4 == 0) atomicAdd(&hist[idx], 1u);
    float4 zv = *(const float4*)(z + (size_t)row * DIM + c4 * 4);
    float4 qv = *(const float4*)(cb + (size_t)idx * DIM + c4 * 4);
    float dx = qv.x - zv.x, dy = qv.y - zv.y, dz = qv.z - zv.z, dw = qv.w - zv.w;
    float4 o;
    o.x = zv.x + dx; o.y = zv.y + dy; o.z = zv.z + dz; o.w = zv.w + dw;
    *(float4*)(qout + (size_t)row * DIM + c4 * 4) = o;
    float ls = dx * dx + dy * dy + dz * dz + dw * dw;
    #pragma unroll
    for (int off = 32; off; off >>= 1) ls += __shfl_down(ls, off, 64);
    __shared__ float wsum[4];
    int lane = threadIdx.x & 63, wv = threadIdx.x >> 6;
    if (lane == 0) wsum[wv] = ls;
    __syncthreads();
    if (threadIdx.x == 0)
        atomicAdd(loss_acc, (double)(wsum[0] + wsum[1] + wsum[2] + wsum[3]));
}

__global__ __launch_bounds__(1024) void vq_finalize(const unsigned* __restrict__ hist,
                                                    const double* __restrict__ loss_acc,
                                                    float* __restrict__ out) {
    __shared__ float red[1024];
    int t = threadIdx.x;
    float p = (float)hist[t] * (1.0f / (float)N_ROWS);
    red[t] = p * logf(p + 1e-10f);
    __syncthreads();
    for (int s = 512; s; s >>= 1) {
        if (t < s) red[t] += red[t + s];
        __syncthreads();
    }
    if (t == 0) {
        out[ZERO_OFF] = 0.0f;
        out[LOSS_OFF] = (float)(0.25 * (*loss_acc) / (double)Q_N);
        out[PERP_OFF] = expf(-red[0]);
    }
}

extern "C" void kernel_launch(void* const* d_in, const int* in_sizes, int n_in,
                              void* d_out, int out_size, void* d_ws, size_t ws_size,
                              hipStream_t stream) {
    const float* z = (const float*)d_in[0];
    const float* cb = (const float*)d_in[1];
    float* out = (float*)d_out;

    float* sen = (float*)d_ws;
    unsigned* hist = (unsigned*)((char*)d_ws + 4096);
    double* loss_acc = (double*)((char*)d_ws + 8192);
    unsigned* count = (unsigned*)((char*)d_ws + 8200);
    float* szn = (float*)((char*)d_ws + 8448);
    unsigned* worklist = (unsigned*)((char*)d_ws + 139520);
    u16* ehi = (u16*)((char*)d_ws + 270592);
    u16* elo = (u16*)((char*)d_ws + 794880);

    u16* zhi = (u16*)d_out;
    u16* zlo = (u16*)d_out + Q_N;

    vq_init<<<1, 1024, 0, stream>>>(hist, loss_acc, count);
    vq_sen<<<KCODES / 4, 256, 0, stream>>>(cb, sen);
    vq_prep_z<<<N_ROWS / 4, 256, 0, stream>>>(z, zhi, zlo, szn);
    vq_split_e<<<(KCODES * DIM) / 1024, 256, 0, stream>>>(cb, ehi, elo);
    vq_mfma<<<N_ROWS / 128, 512, 0, stream>>>(zhi, zlo, ehi, elo, sen,
                                              out + IDX_OFF, count, worklist);
    vq_fixup<<<256, 256, 0, stream>>>(z, cb, sen, szn, count, worklist, out + IDX_OFF);
    vq_gather<<<(N_ROWS * (DIM / 4)) / 256, 256, 0, stream>>>(z, cb, out + IDX_OFF, out, loss_acc, hist);
    vq_finalize<<<1, 1024, 0, stream>>>(hist, loss_acc, out);
}

// Round 6
// 352.119 us; speedup vs baseline: 1.5023x; 1.4892x over previous
//
#include <hip/hip_runtime.h>

#define N_ROWS 32768
#define DIM 256
#define KCODES 1024

#define Q_N (N_ROWS * DIM)          // 8388608
#define IDX_OFF Q_N                 // 8388608
#define ZERO_OFF (Q_N + N_ROWS)     // 8421376
#define LOSS_OFF (ZERO_OFF + 1)
#define PERP_OFF (ZERO_OFF + 2)

// score-scale margin below which np's fp32 rounding could change the argmin;
// fast path (bf16 3-split MFMA) error ~3e-5 worst-case, np quantization ~6e-5.
#define THETA 2.0e-4f

#define TC 32                 // codes per LDS tile
#define NT (KCODES / TC)      // 32 tiles

typedef __attribute__((ext_vector_type(8))) short bf16x8;
typedef __attribute__((ext_vector_type(4))) float f32x4;
typedef unsigned short u16;

// ws layout (bytes):
//   [0, 4096)          sen float[K]
//   [4096, 8192)       hist uint[K]
//   [8192, 8200)       double loss_acc
//   [8200, 8204)       uint ambig_count
//   [8448, 139520)     szn float[32768]  (numpy-pairwise ||z||^2)
//   [139520, 270592)   uint worklist[32768]
//   [270592, 794880)   ehi u16[262144]   (bf16 of -e)
//   [794880, 1319168)  elo u16[262144]   (bf16 of (-e) - ehi)
// zhi/zlo live in d_out's q region until vq_gather overwrites it.

__device__ inline u16 bf16rne(float f) {
    unsigned u = __float_as_uint(f);
    return (u16)((u + 0x7FFFu + ((u >> 16) & 1u)) >> 16);
}
__device__ inline float bf16f(u16 h) { return __uint_as_float((unsigned)h << 16); }

typedef __attribute__((address_space(3))) unsigned int as3_uint;
typedef __attribute__((address_space(1))) const unsigned int as1_uint;
__device__ inline void gload_lds16(const void* g, void* l) {
    __builtin_amdgcn_global_load_lds((as1_uint*)g, (as3_uint*)l, 16, 0, 0);
}

// fused: init(hist/loss/count) + accurate ||e||^2 + negated bf16 hi/lo splits.
// 256 blocks x 256 threads; block handles 4 codebook rows.
__global__ __launch_bounds__(256) void vq_prep_cb(const float* __restrict__ cb,
                                                  float* __restrict__ sen,
                                                  u16* __restrict__ ehi,
                                                  u16* __restrict__ elo,
                                                  unsigned* __restrict__ hist,
                                                  double* __restrict__ loss_acc,
                                                  unsigned* __restrict__ count) {
    int b = blockIdx.x, t = threadIdx.x;
    if (b < 4) {
        hist[b * 256 + t] = 0u;
        if (b == 0 && t == 0) { *loss_acc = 0.0; *count = 0u; }
    }
    int code = b * 4 + (t >> 6);
    int lane = t & 63;
    size_t eoff = (size_t)code * DIM + lane * 4;
    float4 v = *(const float4*)(cb + eoff);
    double s = (double)v.x * v.x + (double)v.y * v.y + (double)v.z * v.z + (double)v.w * v.w;
    #pragma unroll
    for (int off = 32; off; off >>= 1) s += __shfl_down(s, off, 64);
    if (lane == 0) sen[code] = (float)s;
    v.x = -v.x; v.y = -v.y; v.z = -v.z; v.w = -v.w;
    ushort4 h, l;
    h.x = bf16rne(v.x); l.x = bf16rne(v.x - bf16f(h.x));
    h.y = bf16rne(v.y); l.y = bf16rne(v.y - bf16f(h.y));
    h.z = bf16rne(v.z); l.z = bf16rne(v.z - bf16f(h.z));
    h.w = bf16rne(v.w); l.w = bf16rne(v.w - bf16f(h.w));
    *(ushort4*)(ehi + eoff) = h;
    *(ushort4*)(elo + eoff) = l;
}

// fused: z -> bf16 hi/lo splits + numpy-pairwise-exact ||z||^2 (np fp32
// pairwise_sum order reproduced bit-exactly via __fmul_rn/__fadd_rn).
__global__ __launch_bounds__(256) void vq_prep_z(const float* __restrict__ z,
                                                 u16* __restrict__ zhi,
                                                 u16* __restrict__ zlo,
                                                 float* __restrict__ szn) {
    __shared__ float zs[4 * 264];
    size_t base = (size_t)blockIdx.x * 1024;
    int t = threadIdx.x;
    float4 v = *(const float4*)(z + base + t * 4);
    ushort4 h, l;
    h.x = bf16rne(v.x); l.x = bf16rne(v.x - bf16f(h.x));
    h.y = bf16rne(v.y); l.y = bf16rne(v.y - bf16f(h.y));
    h.z = bf16rne(v.z); l.z = bf16rne(v.z - bf16f(h.z));
    h.w = bf16rne(v.w); l.w = bf16rne(v.w - bf16f(h.w));
    *(ushort4*)(zhi + base + t * 4) = h;
    *(ushort4*)(zlo + base + t * 4) = l;
    int rowA = t >> 6, dA = (t & 63) * 4;
    *(float4*)&zs[rowA * 264 + dA] = v;
    __syncthreads();
    if (t < 64) {
        int rowL = t >> 4;
        int sub = t & 15;
        int hb = sub >> 3;
        int j = sub & 7;
        const float* a = zs + rowL * 264 + hb * 128 + j;
        float v0 = a[0];
        float c = __fmul_rn(v0, v0);
        #pragma unroll
        for (int i = 1; i < 16; ++i) {
            float w = a[8 * i];
            c = __fadd_rn(c, __fmul_rn(w, w));
        }
        float p;
        p = __shfl_xor(c, 1, 64); c = __fadd_rn(c, p);
        p = __shfl_xor(c, 2, 64); c = __fadd_rn(c, p);
        p = __shfl_xor(c, 4, 64); c = __fadd_rn(c, p);
        p = __shfl_xor(c, 8, 64); c = __fadd_rn(c, p);
        if (sub == 0) szn[blockIdx.x * 4 + rowL] = c;
    }
}

// MFMA distance-argmin with LDS-staged e tiles.
// 256 blocks x 8 waves x 16 rows. e-splits staged per 32-code tile via
// global_load_lds (coalesced, 8x L2-traffic reduction vs per-wave loads),
// double-buffered. T2 XOR-swizzle (chunk ^= (code&7)) applied as
// inverse-swizzled SOURCE + swizzled READ (linear LDS dest, rule 21):
// 16B chunk lin = lc*32 + dc*4 + koct, phys = lin ^ ((lin>>5)&7).
// LDS bytes are bit-identical to the old global operands -> same MFMA math.
__global__ __launch_bounds__(512, 2) void vq_mfma(const u16* __restrict__ zhi,
                                                  const u16* __restrict__ zlo,
                                                  const u16* __restrict__ ehi,
                                                  const u16* __restrict__ elo,
                                                  const float* __restrict__ sen,
                                                  float* __restrict__ idx_out,
                                                  unsigned* __restrict__ count,
                                                  unsigned* __restrict__ worklist) {
    __shared__ char lds[2][32768];   // per buffer: [0,16K) ehi tile, [16K,32K) elo tile
    const int tid = threadIdx.x;
    const int wid = tid >> 6;
    const int lane = tid & 63;
    const int col16 = lane & 15;
    const int koct = lane >> 4;
    const int s3 = col16 & 7;
    const int rowbase = blockIdx.x * 128 + wid * 16;
    const int zrow = rowbase + col16;

    // A fragments: 8 d-chunks x {hi,lo} (live in AGPRs; MFMA reads A from AGPR)
    bf16x8 zh[8], zl[8];
    {
        const u16* ph = zhi + (size_t)zrow * DIM + koct * 8;
        const u16* pl = zlo + (size_t)zrow * DIM + koct * 8;
        #pragma unroll
        for (int dc = 0; dc < 8; ++dc) {
            zh[dc] = *(const bf16x8*)(ph + dc * 32);
            zl[dc] = *(const bf16x8*)(pl + dc * 32);
        }
    }

    float best[4]   = {3.4e38f, 3.4e38f, 3.4e38f, 3.4e38f};
    float second[4] = {3.4e38f, 3.4e38f, 3.4e38f, 3.4e38f};
    int   besti[4]  = {0, 0, 0, 0};

    // stage tile tt into buffer b: 2048 chunks of 16B ([0,1024)=ehi, rest=elo)
    auto STAGE = [&](int tt, int b) {
        #pragma unroll
        for (int r = 0; r < 4; ++r) {
            int p = r * 512 + wid * 64 + lane;
            int q = p & 1023;
            int src = q ^ ((q >> 5) & 7);          // inverse swizzle (involution)
            const char* sp = ((p >> 10) ? (const char*)elo : (const char*)ehi)
                             + (size_t)tt * 16384 + src * 16;
            gload_lds16(sp, &lds[b][(r * 512 + wid * 64) * 16]);
        }
    };

    STAGE(0, 0);
    __syncthreads();

    for (int tt = 0; tt < NT; ++tt) {
        if (tt + 1 < NT) STAGE(tt + 1, (tt + 1) & 1);
        const char* bb = lds[tt & 1];
        #pragma unroll
        for (int ct = 0; ct < 2; ++ct) {
            const int lc = ct * 16 + col16;
            const int c = tt * TC + lc;
            const float sh = 0.5f * sen[c];
            const int rbase = lc * 512;            // bytes within part
            f32x4 aHH = {0.f, 0.f, 0.f, 0.f};
            f32x4 aLH = {0.f, 0.f, 0.f, 0.f};
            f32x4 aHL = {0.f, 0.f, 0.f, 0.f};
            #pragma unroll
            for (int dc = 0; dc < 8; ++dc) {
                int off = ((dc * 4 + koct) ^ s3) * 16;   // swizzled read
                bf16x8 bh = *(const bf16x8*)(bb + rbase + off);
                bf16x8 bl = *(const bf16x8*)(bb + 16384 + rbase + off);
                aHH = __builtin_amdgcn_mfma_f32_16x16x32_bf16(zh[dc], bh, aHH, 0, 0, 0);
                aLH = __builtin_amdgcn_mfma_f32_16x16x32_bf16(zl[dc], bh, aLH, 0, 0, 0);
                aHL = __builtin_amdgcn_mfma_f32_16x16x32_bf16(zh[dc], bl, aHL, 0, 0, 0);
            }
            #pragma unroll
            for (int r = 0; r < 4; ++r) {
                float s = sh + (aHH[r] + (aLH[r] + aHL[r]));
                if (s < best[r]) { second[r] = best[r]; best[r] = s; besti[r] = c; }
                else if (s < second[r]) { second[r] = s; }
            }
        }
        __syncthreads();   // drains global_load_lds (vmcnt 0) + protects buffers
    }

    #pragma unroll
    for (int r = 0; r < 4; ++r) {
        float v1 = best[r], v2 = second[r];
        int i1 = besti[r];
        #pragma unroll
        for (int m = 1; m < 16; m <<= 1) {
            float ov1 = __shfl_xor(v1, m, 64);
            int   oi1 = __shfl_xor(i1, m, 64);
            float ov2 = __shfl_xor(v2, m, 64);
            if (ov1 < v1 || (ov1 == v1 && oi1 < i1)) {
                v2 = fminf(v1, ov2); v1 = ov1; i1 = oi1;
            } else {
                v2 = fminf(v2, ov1);
            }
        }
        if (col16 == 0) {
            int row = rowbase + koct * 4 + r;
            idx_out[row] = (float)i1;
            if (v2 - v1 < 0.5f * THETA) {   // acc is score/2
                unsigned slot = atomicAdd(count, 1u);
                worklist[slot] = (unsigned)row;
            }
        }
    }
}

// np-fp32 emulation for ambiguous rows (bit-exact vs reference argmin)
__global__ __launch_bounds__(256) void vq_fixup(const float* __restrict__ z,
                                                const float* __restrict__ cb,
                                                const float* __restrict__ sen,
                                                const float* __restrict__ szn,
                                                const unsigned* __restrict__ count,
                                                const unsigned* __restrict__ worklist,
                                                float* __restrict__ idx_out) {
    __shared__ float zrow[DIM];
    __shared__ float rv[256];
    __shared__ int ri[256];
    int t = threadIdx.x;
    int n = (int)*count;
    for (int w = blockIdx.x; w < n; w += gridDim.x) {
        int row = (int)worklist[w];
        float sz = szn[row];
        zrow[t] = z[(size_t)row * DIM + t];
        __syncthreads();
        float bv = 3.4e38f;
        int bi = 0x7fffffff;
        #pragma unroll
        for (int cc = 0; cc < 4; ++cc) {
            int cI = t + 256 * cc;
            const float* e = cb + (size_t)cI * DIM;
            double dot = 0.0;
            for (int d = 0; d < DIM; d += 4) {
                float4 ev = *(const float4*)(e + d);
                dot += (double)ev.x * zrow[d + 0] + (double)ev.y * zrow[d + 1]
                     + (double)ev.z * zrow[d + 2] + (double)ev.w * zrow[d + 3];
            }
            float dotx = (float)dot;
            float A = __fadd_rn(sz, sen[cI]);
            float dref = __fmaf_rn(-2.0f, dotx, A);
            if (dref < bv) { bv = dref; bi = cI; }
        }
        rv[t] = bv; ri[t] = bi;
        __syncthreads();
        for (int s = 128; s; s >>= 1) {
            if (t < s) {
                if (rv[t + s] < rv[t] || (rv[t + s] == rv[t] && ri[t + s] < ri[t])) {
                    rv[t] = rv[t + s]; ri[t] = ri[t + s];
                }
            }
            __syncthreads();
        }
        if (t == 0) idx_out[row] = (float)ri[0];
        __syncthreads();
    }
}

// quantized_ste = z + (q - z); commitment loss; histogram from final idx
__global__ __launch_bounds__(256) void vq_gather(const float* __restrict__ z,
                                                 const float* __restrict__ cb,
                                                 const float* __restrict__ idxf,
                                                 float* __restrict__ qout,
                                                 double* __restrict__ loss_acc,
                                                 unsigned* __restrict__ hist) {
    int gid = blockIdx.x * 256 + threadIdx.x;
    int row = gid >> 6, c4 = gid & 63;
    int idx = (int)idxf[row];
    if (c4 == 0) atomicAdd(&hist[idx], 1u);
    float4 zv = *(const float4*)(z + (size_t)row * DIM + c4 * 4);
    float4 qv = *(const float4*)(cb + (size_t)idx * DIM + c4 * 4);
    float dx = qv.x - zv.x, dy = qv.y - zv.y, dz = qv.z - zv.z, dw = qv.w - zv.w;
    float4 o;
    o.x = zv.x + dx; o.y = zv.y + dy; o.z = zv.z + dz; o.w = zv.w + dw;
    *(float4*)(qout + (size_t)row * DIM + c4 * 4) = o;
    float ls = dx * dx + dy * dy + dz * dz + dw * dw;
    #pragma unroll
    for (int off = 32; off; off >>= 1) ls += __shfl_down(ls, off, 64);
    __shared__ float wsum[4];
    int lane = threadIdx.x & 63, wv = threadIdx.x >> 6;
    if (lane == 0) wsum[wv] = ls;
    __syncthreads();
    if (threadIdx.x == 0)
        atomicAdd(loss_acc, (double)(wsum[0] + wsum[1] + wsum[2] + wsum[3]));
}

__global__ __launch_bounds__(1024) void vq_finalize(const unsigned* __restrict__ hist,
                                                    const double* __restrict__ loss_acc,
                                                    float* __restrict__ out) {
    __shared__ float red[1024];
    int t = threadIdx.x;
    float p = (float)hist[t] * (1.0f / (float)N_ROWS);
    red[t] = p * logf(p + 1e-10f);
    __syncthreads();
    for (int s = 512; s; s >>= 1) {
        if (t < s) red[t] += red[t + s];
        __syncthreads();
    }
    if (t == 0) {
        out[ZERO_OFF] = 0.0f;
        out[LOSS_OFF] = (float)(0.25 * (*loss_acc) / (double)Q_N);
        out[PERP_OFF] = expf(-red[0]);
    }
}

extern "C" void kernel_launch(void* const* d_in, const int* in_sizes, int n_in,
                              void* d_out, int out_size, void* d_ws, size_t ws_size,
                              hipStream_t stream) {
    const float* z = (const float*)d_in[0];
    const float* cb = (const float*)d_in[1];
    float* out = (float*)d_out;

    float* sen = (float*)d_ws;
    unsigned* hist = (unsigned*)((char*)d_ws + 4096);
    double* loss_acc = (double*)((char*)d_ws + 8192);
    unsigned* count = (unsigned*)((char*)d_ws + 8200);
    float* szn = (float*)((char*)d_ws + 8448);
    unsigned* worklist = (unsigned*)((char*)d_ws + 139520);
    u16* ehi = (u16*)((char*)d_ws + 270592);
    u16* elo = (u16*)((char*)d_ws + 794880);

    u16* zhi = (u16*)d_out;
    u16* zlo = (u16*)d_out + Q_N;

    vq_prep_cb<<<KCODES / 4, 256, 0, stream>>>(cb, sen, ehi, elo, hist, loss_acc, count);
    vq_prep_z<<<N_ROWS / 4, 256, 0, stream>>>(z, zhi, zlo, szn);
    vq_mfma<<<N_ROWS / 128, 512, 0, stream>>>(zhi, zlo, ehi, elo, sen,
                                              out + IDX_OFF, count, worklist);
    vq_fixup<<<256, 256, 0, stream>>>(z, cb, sen, szn, count, worklist, out + IDX_OFF);
    vq_gather<<<(N_ROWS * (DIM / 4)) / 256, 256, 0, stream>>>(z, cb, out + IDX_OFF, out, loss_acc, hist);
    vq_finalize<<<1, 1024, 0, stream>>>(hist, loss_acc, out);
}